// Round 1
// baseline (14679.886 us; speedup 1.0000x reference)
//
#include <hip/hip_runtime.h>
#include <hip/hip_bf16.h>
#include <math.h>

#define Dm 768
#define Tt 1024
#define Bb 2
#define Hh 12
#define DK 64
#define DFF 4096
#define Ll 12
#define Vv 50257
#define ROWS (Bb*Tt)   // 2048
#define LN_EPS 1e-5f

// ---------------------------------------------------------------------------
// Embedding: x[b,t,:] = tok_emb[idx[b,t],:] + pos_emb[t,:]
// ---------------------------------------------------------------------------
__global__ __launch_bounds__(256) void embed_kernel(
    const int* __restrict__ idx, const float* __restrict__ tok,
    const float* __restrict__ pos, float* __restrict__ x) {
  const int row = blockIdx.x;          // 0..2047
  const int t = row & (Tt - 1);
  const int tok_id = idx[row];
  const float* tsrc = tok + (size_t)tok_id * Dm;
  const float* psrc = pos + (size_t)t * Dm;
  float* dst = x + (size_t)row * Dm;
  for (int i = threadIdx.x; i < Dm; i += 256)
    dst[i] = tsrc[i] + psrc[i];
}

// ---------------------------------------------------------------------------
// LayerNorm (one block of 256 threads per row, D=768 -> 3 elems/thread)
// ---------------------------------------------------------------------------
__global__ __launch_bounds__(256) void ln_kernel(
    const float* __restrict__ x, const float* __restrict__ w,
    const float* __restrict__ b, float* __restrict__ out) {
  const int row = blockIdx.x;
  const int tid = threadIdx.x;
  const float* src = x + (size_t)row * Dm;
  float v[3];
  float sum = 0.f, sq = 0.f;
#pragma unroll
  for (int i = 0; i < 3; i++) {
    v[i] = src[tid + i * 256];
    sum += v[i];
    sq += v[i] * v[i];
  }
#pragma unroll
  for (int off = 32; off > 0; off >>= 1) {
    sum += __shfl_xor(sum, off);
    sq  += __shfl_xor(sq, off);
  }
  __shared__ float red[8];
  const int wid = tid >> 6, lane = tid & 63;
  if (lane == 0) { red[wid] = sum; red[wid + 4] = sq; }
  __syncthreads();
  sum = red[0] + red[1] + red[2] + red[3];
  sq  = red[4] + red[5] + red[6] + red[7];
  const float mu = sum * (1.f / Dm);
  const float var = sq * (1.f / Dm) - mu * mu;
  const float rstd = rsqrtf(var + LN_EPS);
  float* dst = out + (size_t)row * Dm;
#pragma unroll
  for (int i = 0; i < 3; i++) {
    const int d = tid + i * 256;
    dst[d] = (v[i] - mu) * rstd * w[d] + b[d];
  }
}

// ---------------------------------------------------------------------------
// GEMM: C[M,N] = A[M,K] @ B[N,K]^T (+ bias) (+ residual) (+ GELU)
// BM=128, BN=64, BK=16, 256 threads, 8x4 per thread.
// LDS stored K-major-transposed: As[k][m], Bs[k][n] (+4 pad -> 2-way max).
// ---------------------------------------------------------------------------
#define EPI_BIAS 0
#define EPI_BIAS_RES 1
#define EPI_BIAS_GELU 2
#define EPI_NONE 3
#define BM 128
#define BN 64
#define BK 16

template <int EPI>
__global__ __launch_bounds__(256) void gemm_bt(
    const float* __restrict__ A, const float* __restrict__ B,
    const float* __restrict__ bias, const float* __restrict__ res,
    float* __restrict__ C, int M, int N, int K) {
  __shared__ float As[BK][BM + 4];
  __shared__ float Bs[BK][BN + 4];
  const int tid = threadIdx.x;
  const int m0 = blockIdx.y * BM;
  const int n0 = blockIdx.x * BN;
  const int tx = tid & 15;   // 16 groups * 4 cols = 64
  const int ty = tid >> 4;   // 16 groups * 8 rows = 128
  float acc[8][4];
#pragma unroll
  for (int i = 0; i < 8; i++)
#pragma unroll
    for (int j = 0; j < 4; j++) acc[i][j] = 0.f;

  for (int k0 = 0; k0 < K; k0 += BK) {
    // A tile: 128x16 = 512 float4, 2 per thread
#pragma unroll
    for (int i = 0; i < 2; i++) {
      const int q = tid + i * 256;
      const int row = q >> 2, kq = (q & 3) * 4;
      const float4 v = *(const float4*)&A[(size_t)(m0 + row) * K + k0 + kq];
      As[kq + 0][row] = v.x; As[kq + 1][row] = v.y;
      As[kq + 2][row] = v.z; As[kq + 3][row] = v.w;
    }
    // B tile: 64x16 = 256 float4, 1 per thread (guard n<N for head gemm)
    {
      const int row = tid >> 2, kq = (tid & 3) * 4;
      const int n = n0 + row;
      float4 v = make_float4(0.f, 0.f, 0.f, 0.f);
      if (n < N) v = *(const float4*)&B[(size_t)n * K + k0 + kq];
      Bs[kq + 0][row] = v.x; Bs[kq + 1][row] = v.y;
      Bs[kq + 2][row] = v.z; Bs[kq + 3][row] = v.w;
    }
    __syncthreads();
#pragma unroll
    for (int kk = 0; kk < BK; kk++) {
      const float4 a0 = *(const float4*)&As[kk][ty * 8];
      const float4 a1 = *(const float4*)&As[kk][ty * 8 + 4];
      const float4 bv = *(const float4*)&Bs[kk][tx * 4];
      const float a[8] = {a0.x, a0.y, a0.z, a0.w, a1.x, a1.y, a1.z, a1.w};
      const float bb[4] = {bv.x, bv.y, bv.z, bv.w};
#pragma unroll
      for (int i = 0; i < 8; i++)
#pragma unroll
        for (int j = 0; j < 4; j++) acc[i][j] += a[i] * bb[j];
    }
    __syncthreads();
  }
#pragma unroll
  for (int i = 0; i < 8; i++) {
    const int m = m0 + ty * 8 + i;
#pragma unroll
    for (int j = 0; j < 4; j++) {
      const int n = n0 + tx * 4 + j;
      if (n >= N) continue;
      float v = acc[i][j];
      if (EPI != EPI_NONE) v += bias[n];
      if (EPI == EPI_BIAS_RES) v += res[(size_t)m * N + n];
      if (EPI == EPI_BIAS_GELU) v = 0.5f * v * (1.f + erff(v * 0.70710678118654752f));
      C[(size_t)m * N + n] = v;
    }
  }
}

// ---------------------------------------------------------------------------
// Flash attention fp32. Block = 256 threads = 64 q-rows (4 lanes/row).
// grid = (T/64, H, B). K/V tiles (64x64) staged in LDS. Online softmax.
// qkv layout: [row, 3*D] with Q at col h*64, K at 768+h*64, V at 1536+h*64.
// Output y: [row, D] at col h*64.
// ---------------------------------------------------------------------------
__global__ __launch_bounds__(256) void attn_kernel(
    const float* __restrict__ qkv, float* __restrict__ y) {
  __shared__ float Ks[64][64];
  __shared__ float Vs[64][64];
  const int b = blockIdx.z, h = blockIdx.y, rt = blockIdx.x;
  const int tid = threadIdx.x;
  const int sub = tid & 3;        // 4 lanes per row, 16 dims each
  const int rowL = tid >> 2;      // 0..63
  const int row = rt * 64 + rowL; // global q row within T
  const float scale = 0.125f;     // 1/sqrt(64)

  // load q segment (16 floats) into regs
  const float* qsrc = qkv + ((size_t)(b * Tt + row)) * (3 * Dm) + h * DK + sub * 16;
  float q[16];
#pragma unroll
  for (int i = 0; i < 4; i++) {
    const float4 v = *(const float4*)&qsrc[i * 4];
    q[i * 4 + 0] = v.x; q[i * 4 + 1] = v.y; q[i * 4 + 2] = v.z; q[i * 4 + 3] = v.w;
  }

  float m = -INFINITY, l = 0.f;
  float o[16];
#pragma unroll
  for (int i = 0; i < 16; i++) o[i] = 0.f;

  for (int kt = 0; kt <= rt; kt++) {
    // stage K and V tiles: 64 rows x 64 floats each = 1024 float4 each
#pragma unroll
    for (int i = 0; i < 4; i++) {
      const int f = tid + i * 256;
      const int r = f >> 4, c4 = (f & 15) * 4;
      const size_t base = ((size_t)(b * Tt + kt * 64 + r)) * (3 * Dm) + h * DK + c4;
      *(float4*)&Ks[r][c4] = *(const float4*)&qkv[base + Dm];
      *(float4*)&Vs[r][c4] = *(const float4*)&qkv[base + 2 * Dm];
    }
    __syncthreads();
    const int jmax = (kt == rt) ? (rowL + 1) : 64;
    for (int j = 0; j < jmax; j++) {
      // partial dot over this lane's 16 dims
      float s = 0.f;
#pragma unroll
      for (int i = 0; i < 16; i++) s += q[i] * Ks[j][sub * 16 + i];
      s += __shfl_xor(s, 1);
      s += __shfl_xor(s, 2);          // all 4 lanes in quad now have full dot
      s *= scale;
      const float m_new = fmaxf(m, s);
      const float corr = __expf(m - m_new);   // 0 when m == -inf
      const float p = __expf(s - m_new);
      l = l * corr + p;
#pragma unroll
      for (int i = 0; i < 16; i++)
        o[i] = o[i] * corr + p * Vs[j][sub * 16 + i];
      m = m_new;
    }
    __syncthreads();
  }
  const float rl = 1.f / l;
  float* dst = y + ((size_t)(b * Tt + row)) * Dm + h * DK + sub * 16;
#pragma unroll
  for (int i = 0; i < 16; i++) dst[i] = o[i] * rl;
}

// ---------------------------------------------------------------------------
extern "C" void kernel_launch(void* const* d_in, const int* in_sizes, int n_in,
                              void* d_out, int out_size, void* d_ws, size_t ws_size,
                              hipStream_t stream) {
  const int* idx = (const int*)d_in[0];
  const float* tok = (const float*)d_in[1];
  const float* pos = (const float*)d_in[2];
  const float* ln1w = (const float*)d_in[3];
  const float* ln1b = (const float*)d_in[4];
  const float* qkvw = (const float*)d_in[5];
  const float* qkvb = (const float*)d_in[6];
  const float* projw = (const float*)d_in[7];
  const float* projb = (const float*)d_in[8];
  const float* ln2w = (const float*)d_in[9];
  const float* ln2b = (const float*)d_in[10];
  const float* ff1w = (const float*)d_in[11];
  const float* ff1b = (const float*)d_in[12];
  const float* ff2w = (const float*)d_in[13];
  const float* ff2b = (const float*)d_in[14];
  const float* lnfw = (const float*)d_in[15];
  const float* lnfb = (const float*)d_in[16];
  const float* headw = (const float*)d_in[17];
  float* out = (float*)d_out;

  float* x   = (float*)d_ws;            // [2048, 768]
  float* h   = x + (size_t)ROWS * Dm;   // [2048, 768]
  float* y   = h + (size_t)ROWS * Dm;   // [2048, 768]
  float* qkv = y + (size_t)ROWS * Dm;   // [2048, 2304]
  float* ff  = qkv + (size_t)ROWS * 3 * Dm; // [2048, 4096]

  embed_kernel<<<ROWS, 256, 0, stream>>>(idx, tok, pos, x);

  for (int l = 0; l < Ll; l++) {
    ln_kernel<<<ROWS, 256, 0, stream>>>(x, ln1w + l * Dm, ln1b + l * Dm, h);
    gemm_bt<EPI_BIAS><<<dim3((3 * Dm) / BN, ROWS / BM), 256, 0, stream>>>(
        h, qkvw + (size_t)l * 3 * Dm * Dm, qkvb + l * 3 * Dm, nullptr, qkv,
        ROWS, 3 * Dm, Dm);
    attn_kernel<<<dim3(Tt / 64, Hh, Bb), 256, 0, stream>>>(qkv, y);
    gemm_bt<EPI_BIAS_RES><<<dim3(Dm / BN, ROWS / BM), 256, 0, stream>>>(
        y, projw + (size_t)l * Dm * Dm, projb + l * Dm, x, x, ROWS, Dm, Dm);
    ln_kernel<<<ROWS, 256, 0, stream>>>(x, ln2w + l * Dm, ln2b + l * Dm, h);
    gemm_bt<EPI_BIAS_GELU><<<dim3(DFF / BN, ROWS / BM), 256, 0, stream>>>(
        h, ff1w + (size_t)l * DFF * Dm, ff1b + l * DFF, nullptr, ff,
        ROWS, DFF, Dm);
    gemm_bt<EPI_BIAS_RES><<<dim3(Dm / BN, ROWS / BM), 256, 0, stream>>>(
        ff, ff2w + (size_t)l * Dm * DFF, ff2b + l * Dm, x, x, ROWS, Dm, DFF);
  }

  ln_kernel<<<ROWS, 256, 0, stream>>>(x, lnfw, lnfb, h);
  gemm_bt<EPI_NONE><<<dim3((Vv + BN - 1) / BN, ROWS / BM), 256, 0, stream>>>(
      h, headw, nullptr, nullptr, out, ROWS, Vv, Dm);
}

// Round 2
// 5362.381 us; speedup vs baseline: 2.7376x; 2.7376x over previous
//
#include <hip/hip_runtime.h>
#include <hip/hip_bf16.h>
#include <math.h>

#define Dm 768
#define Tt 1024
#define Bb 2
#define Hh 12
#define DFF 4096
#define Ll 12
#define Vv 50257
#define ROWS (Bb*Tt)   // 2048
#define LN_EPS 1e-5f

typedef unsigned int uint;
typedef unsigned short ushort;
typedef float f32x4 __attribute__((ext_vector_type(4)));
typedef short bf16x8 __attribute__((ext_vector_type(8)));

__device__ __forceinline__ ushort f2bf(float f) {
  uint u = __builtin_bit_cast(uint, f);
  u += 0x7FFFu + ((u >> 16) & 1u);   // RNE
  return (ushort)(u >> 16);
}

// ---------------------------------------------------------------------------
// Embedding (fp32 residual stream)
// ---------------------------------------------------------------------------
__global__ __launch_bounds__(256) void embed_kernel(
    const int* __restrict__ idx, const float* __restrict__ tok,
    const float* __restrict__ pos, float* __restrict__ x) {
  const int row = blockIdx.x;
  const int t = row & (Tt - 1);
  const float* tsrc = tok + (size_t)idx[row] * Dm;
  const float* psrc = pos + (size_t)t * Dm;
  float* dst = x + (size_t)row * Dm;
  for (int i = threadIdx.x; i < Dm; i += 256) dst[i] = tsrc[i] + psrc[i];
}

// ---------------------------------------------------------------------------
// LayerNorm: fp32 in -> bf16 out
// ---------------------------------------------------------------------------
__global__ __launch_bounds__(256) void ln_kernel(
    const float* __restrict__ x, const float* __restrict__ w,
    const float* __restrict__ b, ushort* __restrict__ out) {
  const int row = blockIdx.x;
  const int tid = threadIdx.x;
  const float* src = x + (size_t)row * Dm;
  float v[3];
  float sum = 0.f, sq = 0.f;
#pragma unroll
  for (int i = 0; i < 3; i++) {
    v[i] = src[tid + i * 256];
    sum += v[i]; sq += v[i] * v[i];
  }
#pragma unroll
  for (int off = 32; off > 0; off >>= 1) {
    sum += __shfl_xor(sum, off);
    sq  += __shfl_xor(sq, off);
  }
  __shared__ float red[8];
  const int wid = tid >> 6, lane = tid & 63;
  if (lane == 0) { red[wid] = sum; red[wid + 4] = sq; }
  __syncthreads();
  sum = red[0] + red[1] + red[2] + red[3];
  sq  = red[4] + red[5] + red[6] + red[7];
  const float mu = sum * (1.f / Dm);
  const float var = sq * (1.f / Dm) - mu * mu;
  const float rstd = rsqrtf(var + LN_EPS);
  ushort* dst = out + (size_t)row * Dm;
#pragma unroll
  for (int i = 0; i < 3; i++) {
    const int d = tid + i * 256;
    dst[d] = f2bf((v[i] - mu) * rstd * w[d] + b[d]);
  }
}

// ---------------------------------------------------------------------------
// Weight converters fp32 -> bf16 (counts in float4 units)
// ---------------------------------------------------------------------------
__global__ __launch_bounds__(256) void convert_w(
    const float* __restrict__ s, ushort* __restrict__ d, int n4) {
  const int stride = gridDim.x * 256;
  for (int i = blockIdx.x * 256 + threadIdx.x; i < n4; i += stride) {
    const float4 v = ((const float4*)s)[i];
    ushort4 o;
    o.x = f2bf(v.x); o.y = f2bf(v.y); o.z = f2bf(v.z); o.w = f2bf(v.w);
    ((ushort4*)d)[i] = o;
  }
}

__global__ __launch_bounds__(256) void convert_w4(
    const float* __restrict__ s0, const float* __restrict__ s1,
    const float* __restrict__ s2, const float* __restrict__ s3,
    ushort* __restrict__ d, int c0, int c1, int c2, int c3) {
  const int total = c0 + c1 + c2 + c3;
  const int stride = gridDim.x * 256;
  for (int i = blockIdx.x * 256 + threadIdx.x; i < total; i += stride) {
    int j = i; const float* s;
    if (j < c0) s = s0;
    else if ((j -= c0) < c1) s = s1;
    else if ((j -= c1) < c2) s = s2;
    else { j -= c2; s = s3; }
    const float4 v = ((const float4*)s)[j];
    ushort4 o;
    o.x = f2bf(v.x); o.y = f2bf(v.y); o.z = f2bf(v.z); o.w = f2bf(v.w);
    ((ushort4*)d)[i] = o;
  }
}

// ---------------------------------------------------------------------------
// bf16 MFMA GEMM: C[M,Nloc] = A[M,K](bf16) @ B[Nloc,K](bf16)^T + epilogue
// 128x128 tile, BK=32, 4 waves (2x2 of 64x64), mfma_f32_16x16x32_bf16.
// global_load_lds w/ pre-swizzled source; swizzled ds_read_b128 (2-way max).
// Swizzle: chunk' = chunk ^ ((row>>1)&3)  (4x 16B chunks per 64B row)
// ---------------------------------------------------------------------------
#define EPI_BIAS 0
#define EPI_BIAS_RES 1
#define EPI_BIAS_GELU 2
#define EPI_NONE 3

#define GLL(gp, loff)                                                        \
  __builtin_amdgcn_global_load_lds(                                          \
      (const __attribute__((address_space(1))) uint*)(gp),                   \
      (__attribute__((address_space(3))) uint*)(lds + (loff)), 16, 0, 0)

template <int EPI>
__global__ __launch_bounds__(256) void gemm_mfma(
    const ushort* __restrict__ A, const ushort* __restrict__ B,
    const float* __restrict__ bias, const float* __restrict__ res,
    void* __restrict__ Cv, int K, int Nloc, int ldC) {
  __shared__ char lds[32768];           // 2 x (A 8KB + B 8KB)
  const int tid = threadIdx.x;
  const int l = tid & 63;
  const int wid = __builtin_amdgcn_readfirstlane(tid >> 6);
  const int wr = wid >> 1, wc = wid & 1;
  const int m0 = blockIdx.y * 128;
  const int n0 = blockIdx.x * 128;

  // ---- staging source addresses (pre-swizzled chunk) ----
  const int cperm = (((l & 3) ^ ((l >> 3) & 3)) * 8);      // element offset
  const ushort* gA = A + (size_t)(m0 + wid * 32 + (l >> 2)) * K + cperm;
  int rB = n0 + wid * 32 + (l >> 2);
  rB = min(rB, Nloc - 1);
  const ushort* gB = B + (size_t)rB * K + cperm;

  // ---- ds_read fragment offsets (swizzled) ----
  const int rdSw = (l & 15) * 64 + (((l >> 4) ^ ((l >> 1) & 3)) * 16);
  const int aRd = wr * 4096 + rdSw;
  const int bRd = 8192 + wc * 4096 + rdSw;

  f32x4 acc[4][4] = {};
  const int nt = K / 32;

  // stage tile 0
  {
    const int lb = wid * 2048;
    GLL(gA, lb);            GLL(gA + 16 * K, lb + 1024);
    GLL(gB, 8192 + lb);     GLL(gB + 16 * K, 8192 + lb + 1024);
  }

  for (int t = 0; t < nt; ++t) {
    __syncthreads();                     // tile t resident in buf t&1
    if (t + 1 < nt) {                    // prefetch t+1 into other buffer
      const int base = ((t + 1) & 1) * 16384;
      const int lb = base + wid * 2048;
      const ushort* a = gA + (t + 1) * 32;
      const ushort* b = gB + (t + 1) * 32;
      GLL(a, lb);           GLL(a + 16 * K, lb + 1024);
      GLL(b, 8192 + lb);    GLL(b + 16 * K, 8192 + lb + 1024);
    }
    const int base = (t & 1) * 16384;
    bf16x8 av[4], bv[4];
#pragma unroll
    for (int i = 0; i < 4; ++i) {
      av[i] = *(const bf16x8*)(lds + base + aRd + i * 1024);
      bv[i] = *(const bf16x8*)(lds + base + bRd + i * 1024);
    }
#pragma unroll
    for (int i = 0; i < 4; ++i)
#pragma unroll
      for (int j = 0; j < 4; ++j)
        acc[i][j] = __builtin_amdgcn_mfma_f32_16x16x32_bf16(
            av[i], bv[j], acc[i][j], 0, 0, 0);
  }

  // ---- epilogue: C/D frag layout col=l&15, row=(l>>4)*4+r ----
#pragma unroll
  for (int fm = 0; fm < 4; ++fm) {
    const int row0 = m0 + wr * 64 + fm * 16 + (l >> 4) * 4;
#pragma unroll
    for (int fn = 0; fn < 4; ++fn) {
      const int col = n0 + wc * 64 + fn * 16 + (l & 15);
      if (col >= Nloc) continue;
      float bi = 0.f;
      if (EPI != EPI_NONE) bi = bias[col];
#pragma unroll
      for (int r = 0; r < 4; ++r) {
        float v = acc[fm][fn][r] + bi;
        const size_t off = (size_t)(row0 + r) * ldC + col;
        if (EPI == EPI_BIAS_RES) v += res[off];
        if (EPI == EPI_BIAS_GELU) {
          v = 0.5f * v * (1.f + erff(v * 0.70710678118654752f));
          ((ushort*)Cv)[off] = f2bf(v);
        } else {
          ((float*)Cv)[off] = v;
        }
      }
    }
  }
}

// ---------------------------------------------------------------------------
// Flash attention fp32 (qkv fp32 in, y bf16 out). 256 thr = 64 q-rows.
// ---------------------------------------------------------------------------
__global__ __launch_bounds__(256) void attn_kernel(
    const float* __restrict__ qkv, ushort* __restrict__ y) {
  __shared__ float Ks[64][64];
  __shared__ float Vs[64][64];
  const int b = blockIdx.z, h = blockIdx.y, rt = blockIdx.x;
  const int tid = threadIdx.x;
  const int sub = tid & 3;
  const int rowL = tid >> 2;
  const int row = rt * 64 + rowL;
  const float scale = 0.125f;

  const float* qsrc = qkv + ((size_t)(b * Tt + row)) * (3 * Dm) + h * 64 + sub * 16;
  float q[16];
#pragma unroll
  for (int i = 0; i < 4; i++) {
    const float4 v = *(const float4*)&qsrc[i * 4];
    q[i*4+0] = v.x; q[i*4+1] = v.y; q[i*4+2] = v.z; q[i*4+3] = v.w;
  }
  float m = -INFINITY, lsum = 0.f;
  float o[16];
#pragma unroll
  for (int i = 0; i < 16; i++) o[i] = 0.f;

  for (int kt = 0; kt <= rt; kt++) {
#pragma unroll
    for (int i = 0; i < 4; i++) {
      const int f = tid + i * 256;
      const int r = f >> 4, c4 = (f & 15) * 4;
      const size_t base = ((size_t)(b * Tt + kt * 64 + r)) * (3 * Dm) + h * 64 + c4;
      *(float4*)&Ks[r][c4] = *(const float4*)&qkv[base + Dm];
      *(float4*)&Vs[r][c4] = *(const float4*)&qkv[base + 2 * Dm];
    }
    __syncthreads();
    const int jmax = (kt == rt) ? (rowL + 1) : 64;
    for (int j = 0; j < jmax; j++) {
      float s = 0.f;
#pragma unroll
      for (int i = 0; i < 16; i++) s += q[i] * Ks[j][sub * 16 + i];
      s += __shfl_xor(s, 1);
      s += __shfl_xor(s, 2);
      s *= scale;
      const float m_new = fmaxf(m, s);
      const float corr = __expf(m - m_new);
      const float p = __expf(s - m_new);
      lsum = lsum * corr + p;
#pragma unroll
      for (int i = 0; i < 16; i++)
        o[i] = o[i] * corr + p * Vs[j][sub * 16 + i];
      m = m_new;
    }
    __syncthreads();
  }
  const float rl = 1.f / lsum;
  ushort* dst = y + ((size_t)(b * Tt + row)) * Dm + h * 64 + sub * 16;
#pragma unroll
  for (int i = 0; i < 16; i++) dst[i] = f2bf(o[i] * rl);
}

// ---------------------------------------------------------------------------
extern "C" void kernel_launch(void* const* d_in, const int* in_sizes, int n_in,
                              void* d_out, int out_size, void* d_ws, size_t ws_size,
                              hipStream_t stream) {
  const int* idx = (const int*)d_in[0];
  const float* tok = (const float*)d_in[1];
  const float* pos = (const float*)d_in[2];
  const float* ln1w = (const float*)d_in[3];
  const float* ln1b = (const float*)d_in[4];
  const float* qkvw = (const float*)d_in[5];
  const float* qkvb = (const float*)d_in[6];
  const float* projw = (const float*)d_in[7];
  const float* projb = (const float*)d_in[8];
  const float* ln2w = (const float*)d_in[9];
  const float* ln2b = (const float*)d_in[10];
  const float* ff1w = (const float*)d_in[11];
  const float* ff1b = (const float*)d_in[12];
  const float* ff2w = (const float*)d_in[13];
  const float* ff2b = (const float*)d_in[14];
  const float* lnfw = (const float*)d_in[15];
  const float* lnfb = (const float*)d_in[16];
  const float* headw = (const float*)d_in[17];
  float* out = (float*)d_out;

  char* ws = (char*)d_ws;
  ushort* h   = (ushort*)ws;                    // 3,145,728 B  (bf16 LN out)
  float*  x   = (float*) (ws + 3145728);        // 6,291,456    (fp32 residual)
  ushort* y   = (ushort*)(ws + 9437184);        // 3,145,728    (bf16 attn out)
  float*  qkv = (float*) (ws + 12582912);       // 18,874,368   (fp32 qkv)
  ushort* ff  = (ushort*)(ws + 31457280);       // 16,777,216   (bf16 gelu out)
  ushort* wb  = (ushort*)(ws + 48234496);       // 17,301,504   (bf16 layer weights)
  ushort* hb  = (ushort*)(ws + 3145728);        // head chunk buf (overlays x..wb)

  const int oProj = 3 * Dm * Dm;                // elem offsets inside wb
  const int oFF1  = oProj + Dm * Dm;
  const int oFF2  = oFF1 + DFF * Dm;

  embed_kernel<<<ROWS, 256, 0, stream>>>(idx, tok, pos, x);

  for (int l = 0; l < Ll; l++) {
    convert_w4<<<2048, 256, 0, stream>>>(
        qkvw + (size_t)l * 3 * Dm * Dm, projw + (size_t)l * Dm * Dm,
        ff1w + (size_t)l * DFF * Dm, ff2w + (size_t)l * Dm * DFF, wb,
        3 * Dm * Dm / 4, Dm * Dm / 4, DFF * Dm / 4, Dm * DFF / 4);
    ln_kernel<<<ROWS, 256, 0, stream>>>(x, ln1w + l * Dm, ln1b + l * Dm, h);
    gemm_mfma<EPI_BIAS><<<dim3(18, 16), 256, 0, stream>>>(
        h, wb, qkvb + l * 3 * Dm, nullptr, qkv, Dm, 3 * Dm, 3 * Dm);
    attn_kernel<<<dim3(Tt / 64, Hh, Bb), 256, 0, stream>>>(qkv, y);
    gemm_mfma<EPI_BIAS_RES><<<dim3(6, 16), 256, 0, stream>>>(
        y, wb + oProj, projb + l * Dm, x, x, Dm, Dm, Dm);
    ln_kernel<<<ROWS, 256, 0, stream>>>(x, ln2w + l * Dm, ln2b + l * Dm, h);
    gemm_mfma<EPI_BIAS_GELU><<<dim3(32, 16), 256, 0, stream>>>(
        h, wb + oFF1, ff1b + l * DFF, nullptr, ff, Dm, DFF, DFF);
    gemm_mfma<EPI_BIAS_RES><<<dim3(6, 16), 256, 0, stream>>>(
        ff, wb + oFF2, ff2b + l * Dm, x, x, DFF, Dm, Dm);
  }

  ln_kernel<<<ROWS, 256, 0, stream>>>(x, lnfw, lnfb, h);

  // head in 2 column-chunks (ws reuse)
  const int ch0 = 25088;                        // 196 * 128
  const int ch1 = Vv - ch0;                     // 25169
  convert_w<<<2048, 256, 0, stream>>>(headw, hb, ch0 * (Dm / 4));
  gemm_mfma<EPI_NONE><<<dim3(ch0 / 128, 16), 256, 0, stream>>>(
      h, hb, nullptr, nullptr, out, Dm, ch0, Vv);
  convert_w<<<2048, 256, 0, stream>>>(headw + (size_t)ch0 * Dm, hb, ch1 * (Dm / 4));
  gemm_mfma<EPI_NONE><<<dim3((ch1 + 127) / 128, 16), 256, 0, stream>>>(
      h, hb, nullptr, nullptr, out + ch0, Dm, ch1, Vv);
}

// Round 3
// 2444.247 us; speedup vs baseline: 6.0059x; 2.1939x over previous
//
#include <hip/hip_runtime.h>
#include <hip/hip_bf16.h>
#include <math.h>

#define Dm 768
#define Tt 1024
#define Bb 2
#define Hh 12
#define DFF 4096
#define Ll 12
#define Vv 50257
#define ROWS (Bb*Tt)   // 2048
#define LN_EPS 1e-5f

typedef unsigned int uint;
typedef unsigned short ushort;
typedef float f32x4 __attribute__((ext_vector_type(4)));
typedef short bf16x8 __attribute__((ext_vector_type(8)));
typedef ushort us8 __attribute__((ext_vector_type(8)));

__device__ __forceinline__ ushort f2bf(float f) {
  uint u = __builtin_bit_cast(uint, f);
  u += 0x7FFFu + ((u >> 16) & 1u);   // RNE
  return (ushort)(u >> 16);
}

#define GLL(gp, lp)                                                          \
  __builtin_amdgcn_global_load_lds(                                          \
      (const __attribute__((address_space(1))) uint*)(gp),                   \
      (__attribute__((address_space(3))) uint*)(lp), 16, 0, 0)

// ---------------------------------------------------------------------------
// Embedding (fp32 residual stream)
// ---------------------------------------------------------------------------
__global__ __launch_bounds__(256) void embed_kernel(
    const int* __restrict__ idx, const float* __restrict__ tok,
    const float* __restrict__ pos, float* __restrict__ x) {
  const int row = blockIdx.x;
  const int t = row & (Tt - 1);
  const float* tsrc = tok + (size_t)idx[row] * Dm;
  const float* psrc = pos + (size_t)t * Dm;
  float* dst = x + (size_t)row * Dm;
  for (int i = threadIdx.x; i < Dm; i += 256) dst[i] = tsrc[i] + psrc[i];
}

// ---------------------------------------------------------------------------
// LayerNorm: fp32 in -> bf16 out
// ---------------------------------------------------------------------------
__global__ __launch_bounds__(256) void ln_kernel(
    const float* __restrict__ x, const float* __restrict__ w,
    const float* __restrict__ b, ushort* __restrict__ out) {
  const int row = blockIdx.x;
  const int tid = threadIdx.x;
  const float* src = x + (size_t)row * Dm;
  float v[3];
  float sum = 0.f, sq = 0.f;
#pragma unroll
  for (int i = 0; i < 3; i++) {
    v[i] = src[tid + i * 256];
    sum += v[i]; sq += v[i] * v[i];
  }
#pragma unroll
  for (int off = 32; off > 0; off >>= 1) {
    sum += __shfl_xor(sum, off);
    sq  += __shfl_xor(sq, off);
  }
  __shared__ float red[8];
  const int wid = tid >> 6, lane = tid & 63;
  if (lane == 0) { red[wid] = sum; red[wid + 4] = sq; }
  __syncthreads();
  sum = red[0] + red[1] + red[2] + red[3];
  sq  = red[4] + red[5] + red[6] + red[7];
  const float mu = sum * (1.f / Dm);
  const float var = sq * (1.f / Dm) - mu * mu;
  const float rstd = rsqrtf(var + LN_EPS);
  ushort* dst = out + (size_t)row * Dm;
#pragma unroll
  for (int i = 0; i < 3; i++) {
    const int d = tid + i * 256;
    dst[d] = f2bf((v[i] - mu) * rstd * w[d] + b[d]);
  }
}

// ---------------------------------------------------------------------------
// Weight converters fp32 -> bf16 (counts in float4 units)
// ---------------------------------------------------------------------------
__global__ __launch_bounds__(256) void convert_w(
    const float* __restrict__ s, ushort* __restrict__ d, int n4) {
  const int stride = gridDim.x * 256;
  for (int i = blockIdx.x * 256 + threadIdx.x; i < n4; i += stride) {
    const float4 v = ((const float4*)s)[i];
    ushort4 o;
    o.x = f2bf(v.x); o.y = f2bf(v.y); o.z = f2bf(v.z); o.w = f2bf(v.w);
    ((ushort4*)d)[i] = o;
  }
}

__global__ __launch_bounds__(256) void convert_w4(
    const float* __restrict__ s0, const float* __restrict__ s1,
    const float* __restrict__ s2, const float* __restrict__ s3,
    ushort* __restrict__ d, int c0, int c1, int c2, int c3) {
  const int total = c0 + c1 + c2 + c3;
  const int stride = gridDim.x * 256;
  for (int i = blockIdx.x * 256 + threadIdx.x; i < total; i += stride) {
    int j = i; const float* s;
    if (j < c0) s = s0;
    else if ((j -= c0) < c1) s = s1;
    else if ((j -= c1) < c2) s = s2;
    else { j -= c2; s = s3; }
    const float4 v = ((const float4*)s)[j];
    ushort4 o;
    o.x = f2bf(v.x); o.y = f2bf(v.y); o.z = f2bf(v.z); o.w = f2bf(v.w);
    ((ushort4*)d)[i] = o;
  }
}

// ---------------------------------------------------------------------------
// bf16 MFMA GEMM: C[M,Nloc] = A[M,K](bf16) @ B[Nloc,K](bf16)^T + epilogue
// ---------------------------------------------------------------------------
#define EPI_BIAS 0
#define EPI_BIAS_RES 1
#define EPI_BIAS_GELU 2
#define EPI_NONE 3
#define EPI_QKV 4

template <int EPI>
__global__ __launch_bounds__(256) void gemm_mfma(
    const ushort* __restrict__ A, const ushort* __restrict__ B,
    const float* __restrict__ bias, const float* __restrict__ res,
    void* __restrict__ Cv, int K, int Nloc, int ldC) {
  __shared__ char lds[32768];           // 2 x (A 8KB + B 8KB)
  const int tid = threadIdx.x;
  const int l = tid & 63;
  const int wid = __builtin_amdgcn_readfirstlane(tid >> 6);
  const int wr = wid >> 1, wc = wid & 1;
  const int m0 = blockIdx.y * 128;
  const int n0 = blockIdx.x * 128;

  const int cperm = (((l & 3) ^ ((l >> 3) & 3)) * 8);
  const ushort* gA = A + (size_t)(m0 + wid * 32 + (l >> 2)) * K + cperm;
  int rB = n0 + wid * 32 + (l >> 2);
  rB = min(rB, Nloc - 1);
  const ushort* gB = B + (size_t)rB * K + cperm;

  const int rdSw = (l & 15) * 64 + (((l >> 4) ^ ((l >> 1) & 3)) * 16);
  const int aRd = wr * 4096 + rdSw;
  const int bRd = 8192 + wc * 4096 + rdSw;

  f32x4 acc[4][4] = {};
  const int nt = K / 32;

  {
    const int lb = wid * 2048;
    GLL(gA, lds + lb);          GLL(gA + 16 * K, lds + lb + 1024);
    GLL(gB, lds + 8192 + lb);   GLL(gB + 16 * K, lds + 8192 + lb + 1024);
  }

  for (int t = 0; t < nt; ++t) {
    __syncthreads();
    if (t + 1 < nt) {
      const int base = ((t + 1) & 1) * 16384;
      const int lb = base + wid * 2048;
      const ushort* a = gA + (t + 1) * 32;
      const ushort* b = gB + (t + 1) * 32;
      GLL(a, lds + lb);         GLL(a + 16 * K, lds + lb + 1024);
      GLL(b, lds + 8192 + lb);  GLL(b + 16 * K, lds + 8192 + lb + 1024);
    }
    const int base = (t & 1) * 16384;
    bf16x8 av[4], bv[4];
#pragma unroll
    for (int i = 0; i < 4; ++i) {
      av[i] = *(const bf16x8*)(lds + base + aRd + i * 1024);
      bv[i] = *(const bf16x8*)(lds + base + bRd + i * 1024);
    }
#pragma unroll
    for (int i = 0; i < 4; ++i)
#pragma unroll
      for (int j = 0; j < 4; ++j)
        acc[i][j] = __builtin_amdgcn_mfma_f32_16x16x32_bf16(
            av[i], bv[j], acc[i][j], 0, 0, 0);
  }

#pragma unroll
  for (int fm = 0; fm < 4; ++fm) {
    const int row0 = m0 + wr * 64 + fm * 16 + (l >> 4) * 4;
#pragma unroll
    for (int fn = 0; fn < 4; ++fn) {
      const int col = n0 + wc * 64 + fn * 16 + (l & 15);
      if (col >= Nloc) continue;
      float bi = 0.f;
      if (EPI != EPI_NONE) bi = bias[col];
#pragma unroll
      for (int r = 0; r < 4; ++r) {
        float v = acc[fm][fn][r] + bi;
        const size_t off = (size_t)(row0 + r) * ldC + col;
        if (EPI == EPI_BIAS_RES) v += res[off];
        if (EPI == EPI_BIAS_GELU) {
          v = 0.5f * v * (1.f + erff(v * 0.70710678118654752f));
          ((ushort*)Cv)[off] = f2bf(v);
        } else if (EPI == EPI_QKV) {
          ((ushort*)Cv)[off] = f2bf(v);
        } else {
          ((float*)Cv)[off] = v;
        }
      }
    }
  }
}

// ---------------------------------------------------------------------------
// V transpose: qkv V-part [t][d] -> vT [bh][d][t]   (per (b,h), 64x64 tiles)
// ---------------------------------------------------------------------------
__global__ __launch_bounds__(256) void transpose_v(
    const ushort* __restrict__ qkv, ushort* __restrict__ vTg) {
  __shared__ ushort tile[64][65];
  const int tc = blockIdx.x, bh = blockIdx.y;
  const int b = bh / Hh, h = bh - b * Hh;
  const int tid = threadIdx.x;
#pragma unroll
  for (int i = 0; i < 2; i++) {
    const int c = tid + i * 256;
    const int t = c >> 3, d0 = (c & 7) * 8;
    us8 v = *(const us8*)(qkv + (size_t)(b * Tt + tc * 64 + t) * 2304 +
                          2 * Dm + h * 64 + d0);
#pragma unroll
    for (int j = 0; j < 8; j++) tile[t][d0 + j] = v[j];
  }
  __syncthreads();
#pragma unroll
  for (int i = 0; i < 2; i++) {
    const int c = tid + i * 256;
    const int d = c >> 3, t0 = (c & 7) * 8;
    us8 o;
#pragma unroll
    for (int j = 0; j < 8; j++) o[j] = tile[t0 + j][d];
    *(us8*)(vTg + (size_t)(bh * 64 + d) * Tt + tc * 64 + t0) = o;
  }
}

// ---------------------------------------------------------------------------
// MFMA flash attention. 256 thr = 4 waves; wave w owns q-rows qt*64+w*16..+15.
// K tile [64 kv][64 ch] and VT tile [64 d][64 kv] staged in LDS (dbuf,
// XOR-chunk swizzle, global_load_lds). S via mfma(Q,K); online softmax in
// C-layout; P through per-wave LDS (transpose); O^T = VT·P via mfma.
// ---------------------------------------------------------------------------
__global__ __launch_bounds__(256) void attn_mfma(
    const ushort* __restrict__ qkv, const ushort* __restrict__ vTg,
    ushort* __restrict__ y) {
  __shared__ char lds[40960];   // 2 x {K 8KB, VT 8KB} + P 4x2KB
  const int tid = threadIdx.x;
  const int l = tid & 63;
  const int w = tid >> 6;
  const int s = l & 15, g = l >> 4;
  const int qt = blockIdx.x, h = blockIdx.y, b = blockIdx.z;
  const int bh = b * Hh + h;

  // Q A-fragments (rows qt*64 + w*16 + s)
  const int qrow = qt * 64 + w * 16 + s;
  const ushort* qp = qkv + (size_t)(b * Tt + qrow) * 2304 + h * 64 + g * 8;
  const bf16x8 aq0 = *(const bf16x8*)qp;
  const bf16x8 aq1 = *(const bf16x8*)(qp + 32);

  // staging (chunks c = tid, tid+256; source chunk XOR row&7)
  const int c0 = tid, c1 = tid + 256;
  const int kr0 = c0 >> 3, kr1 = c1 >> 3;
  const ushort* gK0 = qkv + (size_t)(b * Tt + kr0) * 2304 + Dm + h * 64 + ((c0 & 7) ^ (kr0 & 7)) * 8;
  const ushort* gK1 = qkv + (size_t)(b * Tt + kr1) * 2304 + Dm + h * 64 + ((c1 & 7) ^ (kr1 & 7)) * 8;
  const ushort* gV0 = vTg + (size_t)(bh * 64 + kr0) * Tt + ((c0 & 7) ^ (kr0 & 7)) * 8;
  const ushort* gV1 = vTg + (size_t)(bh * 64 + kr1) * Tt + ((c1 & 7) ^ (kr1 & 7)) * 8;
  const int lo0 = c0 * 16, lo1 = c1 * 16;

#define ASTAGE(kt, base)                                                     \
  do {                                                                       \
    const size_t ko = (size_t)(kt) * 64 * 2304;                              \
    const int vo = (kt) * 64;                                                \
    GLL(gK0 + ko, lds + (base) + lo0);                                       \
    GLL(gK1 + ko, lds + (base) + lo1);                                       \
    GLL(gV0 + vo, lds + (base) + 8192 + lo0);                                \
    GLL(gV1 + vo, lds + (base) + 8192 + lo1);                                \
  } while (0)

  f32x4 oc[4] = {};              // O^T: d = fm*16+g*4+r, q = s
  float mrun[4], lrun[4];
#pragma unroll
  for (int r = 0; r < 4; r++) { mrun[r] = -INFINITY; lrun[r] = 0.f; }

  const int pB = 32768 + w * 2048;
  const int kSw = (s & 7);

  ASTAGE(0, 0);
  for (int kt = 0; kt <= qt; ++kt) {
    __syncthreads();                       // buf[kt&1] staged (vmcnt drained)
    if (kt < qt) ASTAGE(kt + 1, ((kt + 1) & 1) * 16384);
    const int cur = (kt & 1) * 16384;

    // ---- S = Q K^T ----
    f32x4 sc[4];
#pragma unroll
    for (int jn = 0; jn < 4; jn++) {
      const int krow = cur + (jn * 16 + s) * 128;
      const bf16x8 bk0 = *(const bf16x8*)(lds + krow + ((g ^ kSw) * 16));
      const bf16x8 bk1 = *(const bf16x8*)(lds + krow + (((4 + g) ^ kSw) * 16));
      f32x4 z = {};
      z = __builtin_amdgcn_mfma_f32_16x16x32_bf16(aq0, bk0, z, 0, 0, 0);
      z = __builtin_amdgcn_mfma_f32_16x16x32_bf16(aq1, bk1, z, 0, 0, 0);
      sc[jn] = z;
    }

    // ---- online softmax (rows q = w*16 + g*4 + r) ----
    float cr[4];
#pragma unroll
    for (int r = 0; r < 4; r++) {
      float v[4];
#pragma unroll
      for (int jn = 0; jn < 4; jn++) {
        v[jn] = sc[jn][r] * 0.125f;
        if (kt == qt && (jn * 16 + s) > (w * 16 + g * 4 + r)) v[jn] = -INFINITY;
      }
      float mx = fmaxf(fmaxf(v[0], v[1]), fmaxf(v[2], v[3]));
      mx = fmaxf(mx, __shfl_xor(mx, 1));
      mx = fmaxf(mx, __shfl_xor(mx, 2));
      mx = fmaxf(mx, __shfl_xor(mx, 4));
      mx = fmaxf(mx, __shfl_xor(mx, 8));
      const float mnew = fmaxf(mrun[r], mx);
      const float corr = __expf(mrun[r] - mnew);
      mrun[r] = mnew;
      float ps = 0.f;
#pragma unroll
      for (int jn = 0; jn < 4; jn++) {
        const float p = __expf(v[jn] - mnew);
        ps += p;
        // P[q][kv] bf16, chunk ^= q>>2 (=g)
        *(ushort*)(lds + pB + (g * 4 + r) * 128 +
                   (((2 * jn + (s >> 3)) ^ g) * 16) + (s & 7) * 2) = f2bf(p);
      }
      ps += __shfl_xor(ps, 1);
      ps += __shfl_xor(ps, 2);
      ps += __shfl_xor(ps, 4);
      ps += __shfl_xor(ps, 8);
      lrun[r] = lrun[r] * corr + ps;
      cr[r] = corr;
    }

    // ---- broadcast corr to O columns (q = s) and rescale ----
    const float c01 = (s & 1) ? cr[1] : cr[0];
    const float c23 = (s & 1) ? cr[3] : cr[2];
    const float csel = (s & 2) ? c23 : c01;
    const float ccol = __shfl(csel, ((s >> 2) << 4) | s);
#pragma unroll
    for (int fm = 0; fm < 4; fm++) {
      oc[fm][0] *= ccol; oc[fm][1] *= ccol;
      oc[fm][2] *= ccol; oc[fm][3] *= ccol;
    }

    // ---- O^T += VT · P ----
    const bf16x8 bp0 = *(const bf16x8*)(lds + pB + s * 128 + ((g ^ (s >> 2)) * 16));
    const bf16x8 bp1 = *(const bf16x8*)(lds + pB + s * 128 + (((4 + g) ^ (s >> 2)) * 16));
#pragma unroll
    for (int fm = 0; fm < 4; fm++) {
      const int vrow = cur + 8192 + (fm * 16 + s) * 128;
      const bf16x8 av0 = *(const bf16x8*)(lds + vrow + ((g ^ kSw) * 16));
      const bf16x8 av1 = *(const bf16x8*)(lds + vrow + (((4 + g) ^ kSw) * 16));
      oc[fm] = __builtin_amdgcn_mfma_f32_16x16x32_bf16(av0, bp0, oc[fm], 0, 0, 0);
      oc[fm] = __builtin_amdgcn_mfma_f32_16x16x32_bf16(av1, bp1, oc[fm], 0, 0, 0);
    }
  }

  // ---- final scale + store ----
  float li[4];
#pragma unroll
  for (int r = 0; r < 4; r++) li[r] = 1.f / lrun[r];
  const float l01 = (s & 1) ? li[1] : li[0];
  const float l23 = (s & 1) ? li[3] : li[2];
  const float lsel = (s & 2) ? l23 : l01;
  const float lcol = __shfl(lsel, ((s >> 2) << 4) | s);
  ushort* yp = y + (size_t)(b * Tt + qrow) * Dm + h * 64;
#pragma unroll
  for (int fm = 0; fm < 4; fm++) {
    ushort4 o4;
    o4.x = f2bf(oc[fm][0] * lcol);
    o4.y = f2bf(oc[fm][1] * lcol);
    o4.z = f2bf(oc[fm][2] * lcol);
    o4.w = f2bf(oc[fm][3] * lcol);
    *(ushort4*)(yp + fm * 16 + g * 4) = o4;
  }
}

// ---------------------------------------------------------------------------
extern "C" void kernel_launch(void* const* d_in, const int* in_sizes, int n_in,
                              void* d_out, int out_size, void* d_ws, size_t ws_size,
                              hipStream_t stream) {
  const int* idx = (const int*)d_in[0];
  const float* tok = (const float*)d_in[1];
  const float* pos = (const float*)d_in[2];
  const float* ln1w = (const float*)d_in[3];
  const float* ln1b = (const float*)d_in[4];
  const float* qkvw = (const float*)d_in[5];
  const float* qkvb = (const float*)d_in[6];
  const float* projw = (const float*)d_in[7];
  const float* projb = (const float*)d_in[8];
  const float* ln2w = (const float*)d_in[9];
  const float* ln2b = (const float*)d_in[10];
  const float* ff1w = (const float*)d_in[11];
  const float* ff1b = (const float*)d_in[12];
  const float* ff2w = (const float*)d_in[13];
  const float* ff2b = (const float*)d_in[14];
  const float* lnfw = (const float*)d_in[15];
  const float* lnfb = (const float*)d_in[16];
  const float* headw = (const float*)d_in[17];
  float* out = (float*)d_out;

  char* ws = (char*)d_ws;
  ushort* h    = (ushort*)ws;                    // [2048][768] bf16
  float*  x    = (float*)(ws + 3145728);         // [2048][768] fp32
  ushort* y    = (ushort*)(ws + 9437184);        // [2048][768] bf16
  ushort* qkv  = (ushort*)(ws + 12582912);       // [2048][2304] bf16
  ushort* vTg  = (ushort*)(ws + 22020096);       // [24][64][1024] bf16
  ushort* ff   = (ushort*)(ws + 25165824);       // [2048][4096] bf16
  ushort* wb   = (ushort*)(ws + 41943040);       // layer weights bf16
  ushort* hb   = (ushort*)(ws + 3145728);        // head chunk (overlay)

  const int oProj = 3 * Dm * Dm;
  const int oFF1  = oProj + Dm * Dm;
  const int oFF2  = oFF1 + DFF * Dm;

  embed_kernel<<<ROWS, 256, 0, stream>>>(idx, tok, pos, x);

  for (int l = 0; l < Ll; l++) {
    convert_w4<<<2048, 256, 0, stream>>>(
        qkvw + (size_t)l * 3 * Dm * Dm, projw + (size_t)l * Dm * Dm,
        ff1w + (size_t)l * DFF * Dm, ff2w + (size_t)l * Dm * DFF, wb,
        3 * Dm * Dm / 4, Dm * Dm / 4, DFF * Dm / 4, Dm * DFF / 4);
    ln_kernel<<<ROWS, 256, 0, stream>>>(x, ln1w + l * Dm, ln1b + l * Dm, h);
    gemm_mfma<EPI_QKV><<<dim3(18, 16), 256, 0, stream>>>(
        h, wb, qkvb + l * 3 * Dm, nullptr, qkv, Dm, 3 * Dm, 3 * Dm);
    transpose_v<<<dim3(16, 24), 256, 0, stream>>>(qkv, vTg);
    attn_mfma<<<dim3(16, Hh, Bb), 256, 0, stream>>>(qkv, vTg, y);
    gemm_mfma<EPI_BIAS_RES><<<dim3(6, 16), 256, 0, stream>>>(
        y, wb + oProj, projb + l * Dm, x, x, Dm, Dm, Dm);
    ln_kernel<<<ROWS, 256, 0, stream>>>(x, ln2w + l * Dm, ln2b + l * Dm, h);
    gemm_mfma<EPI_BIAS_GELU><<<dim3(32, 16), 256, 0, stream>>>(
        h, wb + oFF1, ff1b + l * DFF, nullptr, ff, Dm, DFF, DFF);
    gemm_mfma<EPI_BIAS_RES><<<dim3(6, 16), 256, 0, stream>>>(
        ff, wb + oFF2, ff2b + l * Dm, x, x, DFF, Dm, Dm);
  }

  ln_kernel<<<ROWS, 256, 0, stream>>>(x, lnfw, lnfb, h);

  const int ch0 = 25088;
  const int ch1 = Vv - ch0;
  convert_w<<<2048, 256, 0, stream>>>(headw, hb, ch0 * (Dm / 4));
  gemm_mfma<EPI_NONE><<<dim3(ch0 / 128, 16), 256, 0, stream>>>(
      h, hb, nullptr, nullptr, out, Dm, ch0, Vv);
  convert_w<<<2048, 256, 0, stream>>>(headw + (size_t)ch0 * Dm, hb, ch1 * (Dm / 4));
  gemm_mfma<EPI_NONE><<<dim3((ch1 + 127) / 128, 16), 256, 0, stream>>>(
      h, hb, nullptr, nullptr, out + ch0, Dm, ch1, Vv);
}

// Round 4
// 2145.528 us; speedup vs baseline: 6.8421x; 1.1392x over previous
//
#include <hip/hip_runtime.h>
#include <hip/hip_bf16.h>
#include <math.h>

#define Dm 768
#define Tt 1024
#define Bb 2
#define Hh 12
#define DFF 4096
#define Ll 12
#define Vv 50257
#define ROWS (Bb*Tt)   // 2048
#define LN_EPS 1e-5f

typedef unsigned int uint;
typedef unsigned short ushort;
typedef float f32x4 __attribute__((ext_vector_type(4)));
typedef short bf16x8 __attribute__((ext_vector_type(8)));
typedef ushort us8 __attribute__((ext_vector_type(8)));

__device__ __forceinline__ ushort f2bf(float f) {
  uint u = __builtin_bit_cast(uint, f);
  u += 0x7FFFu + ((u >> 16) & 1u);   // RNE
  return (ushort)(u >> 16);
}

#define GLL(gp, lp)                                                          \
  __builtin_amdgcn_global_load_lds(                                          \
      (const __attribute__((address_space(1))) uint*)(gp),                   \
      (__attribute__((address_space(3))) uint*)(lp), 16, 0, 0)

// ---------------------------------------------------------------------------
// Embedding (fp32 residual stream)
// ---------------------------------------------------------------------------
__global__ __launch_bounds__(256) void embed_kernel(
    const int* __restrict__ idx, const float* __restrict__ tok,
    const float* __restrict__ pos, float* __restrict__ x) {
  const int row = blockIdx.x;
  const int t = row & (Tt - 1);
  const float* tsrc = tok + (size_t)idx[row] * Dm;
  const float* psrc = pos + (size_t)t * Dm;
  float* dst = x + (size_t)row * Dm;
  for (int i = threadIdx.x; i < Dm; i += 256) dst[i] = tsrc[i] + psrc[i];
}

// ---------------------------------------------------------------------------
// LayerNorm: fp32 in -> bf16 out (only used once, after embed)
// ---------------------------------------------------------------------------
__global__ __launch_bounds__(256) void ln_kernel(
    const float* __restrict__ x, const float* __restrict__ w,
    const float* __restrict__ b, ushort* __restrict__ out) {
  const int row = blockIdx.x;
  const int tid = threadIdx.x;
  const float* src = x + (size_t)row * Dm;
  float v[3];
  float sum = 0.f, sq = 0.f;
#pragma unroll
  for (int i = 0; i < 3; i++) {
    v[i] = src[tid + i * 256];
    sum += v[i]; sq += v[i] * v[i];
  }
#pragma unroll
  for (int off = 32; off > 0; off >>= 1) {
    sum += __shfl_xor(sum, off);
    sq  += __shfl_xor(sq, off);
  }
  __shared__ float red[8];
  const int wid = tid >> 6, lane = tid & 63;
  if (lane == 0) { red[wid] = sum; red[wid + 4] = sq; }
  __syncthreads();
  sum = red[0] + red[1] + red[2] + red[3];
  sq  = red[4] + red[5] + red[6] + red[7];
  const float mu = sum * (1.f / Dm);
  const float var = sq * (1.f / Dm) - mu * mu;
  const float rstd = rsqrtf(var + LN_EPS);
  ushort* dst = out + (size_t)row * Dm;
#pragma unroll
  for (int i = 0; i < 3; i++) {
    const int d = tid + i * 256;
    dst[d] = f2bf((v[i] - mu) * rstd * w[d] + b[d]);
  }
}

// ---------------------------------------------------------------------------
// Fused split-K reduce + bias + residual (x += ...) + LayerNorm -> bf16 h
// ---------------------------------------------------------------------------
__global__ __launch_bounds__(256) void red_ln(
    const float* __restrict__ part, int nsk, const float* __restrict__ bias,
    float* __restrict__ x, const float* __restrict__ w,
    const float* __restrict__ b, ushort* __restrict__ out) {
  const int row = blockIdx.x;
  const int tid = threadIdx.x;
  float v[3];
  float sum = 0.f, sq = 0.f;
#pragma unroll
  for (int i = 0; i < 3; i++) {
    const int d = tid + i * 256;
    const size_t off = (size_t)row * Dm + d;
    float s = x[off] + bias[d];
    for (int k = 0; k < nsk; k++) s += part[(size_t)k * ROWS * Dm + off];
    x[off] = s;
    v[i] = s;
    sum += s; sq += s * s;
  }
#pragma unroll
  for (int off = 32; off > 0; off >>= 1) {
    sum += __shfl_xor(sum, off);
    sq  += __shfl_xor(sq, off);
  }
  __shared__ float red[8];
  const int wid = tid >> 6, lane = tid & 63;
  if (lane == 0) { red[wid] = sum; red[wid + 4] = sq; }
  __syncthreads();
  sum = red[0] + red[1] + red[2] + red[3];
  sq  = red[4] + red[5] + red[6] + red[7];
  const float mu = sum * (1.f / Dm);
  const float var = sq * (1.f / Dm) - mu * mu;
  const float rstd = rsqrtf(var + LN_EPS);
  ushort* dst = out + (size_t)row * Dm;
#pragma unroll
  for (int i = 0; i < 3; i++) {
    const int d = tid + i * 256;
    dst[d] = f2bf((v[i] - mu) * rstd * w[d] + b[d]);
  }
}

// ---------------------------------------------------------------------------
// Weight converters fp32 -> bf16 (counts in float4 units)
// ---------------------------------------------------------------------------
__global__ __launch_bounds__(256) void convert_w(
    const float* __restrict__ s, ushort* __restrict__ d, int n4) {
  const int stride = gridDim.x * 256;
  for (int i = blockIdx.x * 256 + threadIdx.x; i < n4; i += stride) {
    const float4 v = ((const float4*)s)[i];
    ushort4 o;
    o.x = f2bf(v.x); o.y = f2bf(v.y); o.z = f2bf(v.z); o.w = f2bf(v.w);
    ((ushort4*)d)[i] = o;
  }
}

__global__ __launch_bounds__(256) void convert_w4(
    const float* __restrict__ s0, const float* __restrict__ s1,
    const float* __restrict__ s2, const float* __restrict__ s3,
    ushort* __restrict__ d, int c0, int c1, int c2, int c3) {
  const int total = c0 + c1 + c2 + c3;
  const int stride = gridDim.x * 256;
  for (int i = blockIdx.x * 256 + threadIdx.x; i < total; i += stride) {
    int j = i; const float* s;
    if (j < c0) s = s0;
    else if ((j -= c0) < c1) s = s1;
    else if ((j -= c1) < c2) s = s2;
    else { j -= c2; s = s3; }
    const float4 v = ((const float4*)s)[j];
    ushort4 o;
    o.x = f2bf(v.x); o.y = f2bf(v.y); o.z = f2bf(v.z); o.w = f2bf(v.w);
    ((ushort4*)d)[i] = o;
  }
}

// ---------------------------------------------------------------------------
// bf16 MFMA GEMM: C[M,Nloc] = A[M,Kloop]@B^T + epi.  Kstr = row stride.
// EPI_PART: blockIdx.z = split-k index; writes fp32 partial [z][row][Nloc].
// ---------------------------------------------------------------------------
#define EPI_QKV 0
#define EPI_PART 1
#define EPI_BIAS_GELU 2
#define EPI_NONE 3

template <int EPI>
__global__ __launch_bounds__(256) void gemm_mfma(
    const ushort* __restrict__ A, const ushort* __restrict__ B,
    const float* __restrict__ bias, void* __restrict__ Cv,
    int Kloop, int Kstr, int Nloc, int ldC) {
  __shared__ char lds[32768];           // 2 x (A 8KB + B 8KB)
  const int tid = threadIdx.x;
  const int l = tid & 63;
  const int wid = __builtin_amdgcn_readfirstlane(tid >> 6);
  const int wr = wid >> 1, wc = wid & 1;
  const int m0 = blockIdx.y * 128;
  const int n0 = blockIdx.x * 128;
  const int z = (EPI == EPI_PART) ? blockIdx.z : 0;
  if (EPI == EPI_PART) { A += (size_t)z * Kloop; B += (size_t)z * Kloop; }

  const int cperm = (((l & 3) ^ ((l >> 3) & 3)) * 8);
  const ushort* gA = A + (size_t)(m0 + wid * 32 + (l >> 2)) * Kstr + cperm;
  int rB = n0 + wid * 32 + (l >> 2);
  rB = min(rB, Nloc - 1);
  const ushort* gB = B + (size_t)rB * Kstr + cperm;

  const int rdSw = (l & 15) * 64 + (((l >> 4) ^ ((l >> 1) & 3)) * 16);
  const int aRd = wr * 4096 + rdSw;
  const int bRd = 8192 + wc * 4096 + rdSw;

  f32x4 acc[4][4] = {};
  const int nt = Kloop / 32;

  {
    const int lb = wid * 2048;
    GLL(gA, lds + lb);          GLL(gA + 16 * Kstr, lds + lb + 1024);
    GLL(gB, lds + 8192 + lb);   GLL(gB + 16 * Kstr, lds + 8192 + lb + 1024);
  }

  for (int t = 0; t < nt; ++t) {
    __syncthreads();
    if (t + 1 < nt) {
      const int base = ((t + 1) & 1) * 16384;
      const int lb = base + wid * 2048;
      const ushort* a = gA + (t + 1) * 32;
      const ushort* b = gB + (t + 1) * 32;
      GLL(a, lds + lb);         GLL(a + 16 * Kstr, lds + lb + 1024);
      GLL(b, lds + 8192 + lb);  GLL(b + 16 * Kstr, lds + 8192 + lb + 1024);
    }
    const int base = (t & 1) * 16384;
    bf16x8 av[4], bv[4];
#pragma unroll
    for (int i = 0; i < 4; ++i) {
      av[i] = *(const bf16x8*)(lds + base + aRd + i * 1024);
      bv[i] = *(const bf16x8*)(lds + base + bRd + i * 1024);
    }
#pragma unroll
    for (int i = 0; i < 4; ++i)
#pragma unroll
      for (int j = 0; j < 4; ++j)
        acc[i][j] = __builtin_amdgcn_mfma_f32_16x16x32_bf16(
            av[i], bv[j], acc[i][j], 0, 0, 0);
  }

#pragma unroll
  for (int fm = 0; fm < 4; ++fm) {
    const int row0 = m0 + wr * 64 + fm * 16 + (l >> 4) * 4;
#pragma unroll
    for (int fn = 0; fn < 4; ++fn) {
      const int col = n0 + wc * 64 + fn * 16 + (l & 15);
      if (col >= Nloc) continue;
      float bi = 0.f;
      if (EPI == EPI_QKV || EPI == EPI_BIAS_GELU) bi = bias[col];
#pragma unroll
      for (int r = 0; r < 4; ++r) {
        float v = acc[fm][fn][r] + bi;
        const size_t off = (size_t)(row0 + r) * ldC + col;
        if (EPI == EPI_BIAS_GELU) {
          v = 0.5f * v * (1.f + erff(v * 0.70710678118654752f));
          ((ushort*)Cv)[off] = f2bf(v);
        } else if (EPI == EPI_QKV) {
          ((ushort*)Cv)[off] = f2bf(v);
        } else if (EPI == EPI_PART) {
          ((float*)Cv)[(size_t)z * ROWS * ldC + off] = v;
        } else {
          ((float*)Cv)[off] = v;
        }
      }
    }
  }
}

// ---------------------------------------------------------------------------
// V transpose: qkv V-part [t][d] -> vT [bh][d][t]
// ---------------------------------------------------------------------------
__global__ __launch_bounds__(256) void transpose_v(
    const ushort* __restrict__ qkv, ushort* __restrict__ vTg) {
  __shared__ ushort tile[64][65];
  const int tc = blockIdx.x, bh = blockIdx.y;
  const int b = bh / Hh, h = bh - b * Hh;
  const int tid = threadIdx.x;
#pragma unroll
  for (int i = 0; i < 2; i++) {
    const int c = tid + i * 256;
    const int t = c >> 3, d0 = (c & 7) * 8;
    us8 v = *(const us8*)(qkv + (size_t)(b * Tt + tc * 64 + t) * 2304 +
                          2 * Dm + h * 64 + d0);
#pragma unroll
    for (int j = 0; j < 8; j++) tile[t][d0 + j] = v[j];
  }
  __syncthreads();
#pragma unroll
  for (int i = 0; i < 2; i++) {
    const int c = tid + i * 256;
    const int d = c >> 3, t0 = (c & 7) * 8;
    us8 o;
#pragma unroll
    for (int j = 0; j < 8; j++) o[j] = tile[t0 + j][d];
    *(us8*)(vTg + (size_t)(bh * 64 + d) * Tt + tc * 64 + t0) = o;
  }
}

// ---------------------------------------------------------------------------
// MFMA flash attention. 128 thr = 2 waves; wave w owns q-rows bq*32+w*16..+15.
// grid (32, H, B). K tile [64kv][64ch] + VT tile [64d][64kv] LDS dbuf.
// ---------------------------------------------------------------------------
__global__ __launch_bounds__(128) void attn_mfma(
    const ushort* __restrict__ qkv, const ushort* __restrict__ vTg,
    ushort* __restrict__ y) {
  __shared__ char lds[36864];   // 2 x {K 8KB, VT 8KB} + P 2x2KB
  const int tid = threadIdx.x;
  const int l = tid & 63;
  const int w = tid >> 6;
  const int s = l & 15, g = l >> 4;
  const int bq = blockIdx.x, h = blockIdx.y, b = blockIdx.z;
  const int bh = b * Hh + h;

  const int qrow = bq * 32 + w * 16 + s;
  const ushort* qp = qkv + (size_t)(b * Tt + qrow) * 2304 + h * 64 + g * 8;
  const bf16x8 aq0 = *(const bf16x8*)qp;
  const bf16x8 aq1 = *(const bf16x8*)(qp + 32);

  // staging: 8 chunks/thread; i<4 -> K tile (chunks 0..511), i>=4 -> VT tile
  size_t gofs[8];
#pragma unroll
  for (int i = 0; i < 8; i++) {
    const int c = tid + i * 128;
    if (i < 4) {
      const int kr = c >> 3;
      gofs[i] = (size_t)(b * Tt + kr) * 2304 + Dm + h * 64 + ((c & 7) ^ (kr & 7)) * 8;
    } else {
      const int cv = c - 512;
      const int vr = cv >> 3;
      gofs[i] = (size_t)(bh * 64 + vr) * Tt + ((cv & 7) ^ (vr & 7)) * 8;
    }
  }

#define ASTAGE(kt, base)                                                     \
  do {                                                                       \
    _Pragma("unroll")                                                        \
    for (int i = 0; i < 8; i++) {                                            \
      const ushort* p = (i < 4) ? (qkv + gofs[i] + (size_t)(kt) * 147456)    \
                                : (vTg + gofs[i] + (kt) * 64);               \
      GLL(p, lds + (base) + tid * 16 + i * 2048);                            \
    }                                                                        \
  } while (0)

  f32x4 oc[4] = {};              // O^T: d = fm*16+g*4+r, q = s
  float mrun[4], lrun[4];
#pragma unroll
  for (int r = 0; r < 4; r++) { mrun[r] = -INFINITY; lrun[r] = 0.f; }

  const int pB = 32768 + w * 2048;
  const int kSw = (s & 7);
  const int nkt = (bq >> 1) + 1;

  ASTAGE(0, 0);
  for (int kt = 0; kt < nkt; ++kt) {
    __syncthreads();
    if (kt + 1 < nkt) ASTAGE(kt + 1, ((kt + 1) & 1) * 16384);
    const int cur = (kt & 1) * 16384;

    // ---- S = Q K^T ----
    f32x4 sc[4];
#pragma unroll
    for (int jn = 0; jn < 4; jn++) {
      const int krow = cur + (jn * 16 + s) * 128;
      const bf16x8 bk0 = *(const bf16x8*)(lds + krow + ((g ^ kSw) * 16));
      const bf16x8 bk1 = *(const bf16x8*)(lds + krow + (((4 + g) ^ kSw) * 16));
      f32x4 z = {};
      z = __builtin_amdgcn_mfma_f32_16x16x32_bf16(aq0, bk0, z, 0, 0, 0);
      z = __builtin_amdgcn_mfma_f32_16x16x32_bf16(aq1, bk1, z, 0, 0, 0);
      sc[jn] = z;
    }

    // ---- online softmax (rows q = bq*32 + w*16 + g*4 + r) ----
    float cr[4];
    const bool diag = (kt == nkt - 1);
#pragma unroll
    for (int r = 0; r < 4; r++) {
      const int rowg = bq * 32 + w * 16 + g * 4 + r;
      float v[4];
#pragma unroll
      for (int jn = 0; jn < 4; jn++) {
        v[jn] = sc[jn][r] * 0.125f;
        if (diag && (kt * 64 + jn * 16 + s) > rowg) v[jn] = -INFINITY;
      }
      float mx = fmaxf(fmaxf(v[0], v[1]), fmaxf(v[2], v[3]));
      mx = fmaxf(mx, __shfl_xor(mx, 1));
      mx = fmaxf(mx, __shfl_xor(mx, 2));
      mx = fmaxf(mx, __shfl_xor(mx, 4));
      mx = fmaxf(mx, __shfl_xor(mx, 8));
      const float mnew = fmaxf(mrun[r], mx);
      const float corr = __expf(mrun[r] - mnew);
      mrun[r] = mnew;
      float ps = 0.f;
#pragma unroll
      for (int jn = 0; jn < 4; jn++) {
        const float p = __expf(v[jn] - mnew);
        ps += p;
        *(ushort*)(lds + pB + (g * 4 + r) * 128 +
                   (((2 * jn + (s >> 3)) ^ g) * 16) + (s & 7) * 2) = f2bf(p);
      }
      ps += __shfl_xor(ps, 1);
      ps += __shfl_xor(ps, 2);
      ps += __shfl_xor(ps, 4);
      ps += __shfl_xor(ps, 8);
      lrun[r] = lrun[r] * corr + ps;
      cr[r] = corr;
    }

    // ---- broadcast corr to O columns (q = s) and rescale ----
    const float c01 = (s & 1) ? cr[1] : cr[0];
    const float c23 = (s & 1) ? cr[3] : cr[2];
    const float csel = (s & 2) ? c23 : c01;
    const float ccol = __shfl(csel, ((s >> 2) << 4) | s);
#pragma unroll
    for (int fm = 0; fm < 4; fm++) {
      oc[fm][0] *= ccol; oc[fm][1] *= ccol;
      oc[fm][2] *= ccol; oc[fm][3] *= ccol;
    }

    // ---- O^T += VT · P ----
    const bf16x8 bp0 = *(const bf16x8*)(lds + pB + s * 128 + ((g ^ (s >> 2)) * 16));
    const bf16x8 bp1 = *(const bf16x8*)(lds + pB + s * 128 + (((4 + g) ^ (s >> 2)) * 16));
#pragma unroll
    for (int fm = 0; fm < 4; fm++) {
      const int vrow = cur + 8192 + (fm * 16 + s) * 128;
      const bf16x8 av0 = *(const bf16x8*)(lds + vrow + ((g ^ kSw) * 16));
      const bf16x8 av1 = *(const bf16x8*)(lds + vrow + (((4 + g) ^ kSw) * 16));
      oc[fm] = __builtin_amdgcn_mfma_f32_16x16x32_bf16(av0, bp0, oc[fm], 0, 0, 0);
      oc[fm] = __builtin_amdgcn_mfma_f32_16x16x32_bf16(av1, bp1, oc[fm], 0, 0, 0);
    }
  }

  float li[4];
#pragma unroll
  for (int r = 0; r < 4; r++) li[r] = 1.f / lrun[r];
  const float l01 = (s & 1) ? li[1] : li[0];
  const float l23 = (s & 1) ? li[3] : li[2];
  const float lsel = (s & 2) ? l23 : l01;
  const float lcol = __shfl(lsel, ((s >> 2) << 4) | s);
  ushort* yp = y + (size_t)(b * Tt + qrow) * Dm + h * 64;
#pragma unroll
  for (int fm = 0; fm < 4; fm++) {
    ushort4 o4;
    o4.x = f2bf(oc[fm][0] * lcol);
    o4.y = f2bf(oc[fm][1] * lcol);
    o4.z = f2bf(oc[fm][2] * lcol);
    o4.w = f2bf(oc[fm][3] * lcol);
    *(ushort4*)(yp + fm * 16 + g * 4) = o4;
  }
}

// ---------------------------------------------------------------------------
extern "C" void kernel_launch(void* const* d_in, const int* in_sizes, int n_in,
                              void* d_out, int out_size, void* d_ws, size_t ws_size,
                              hipStream_t stream) {
  const int* idx = (const int*)d_in[0];
  const float* tok = (const float*)d_in[1];
  const float* pos = (const float*)d_in[2];
  const float* ln1w = (const float*)d_in[3];
  const float* ln1b = (const float*)d_in[4];
  const float* qkvw = (const float*)d_in[5];
  const float* qkvb = (const float*)d_in[6];
  const float* projw = (const float*)d_in[7];
  const float* projb = (const float*)d_in[8];
  const float* ln2w = (const float*)d_in[9];
  const float* ln2b = (const float*)d_in[10];
  const float* ff1w = (const float*)d_in[11];
  const float* ff1b = (const float*)d_in[12];
  const float* ff2w = (const float*)d_in[13];
  const float* ff2b = (const float*)d_in[14];
  const float* lnfw = (const float*)d_in[15];
  const float* lnfb = (const float*)d_in[16];
  const float* headw = (const float*)d_in[17];
  float* out = (float*)d_out;

  char* ws = (char*)d_ws;
  ushort* h    = (ushort*)ws;                    // [2048][768] bf16
  float*  x    = (float*)(ws + 3145728);         // [2048][768] fp32
  ushort* y    = (ushort*)(ws + 9437184);        // [2048][768] bf16
  ushort* qkv  = (ushort*)(ws + 12582912);       // [2048][2304] bf16
  ushort* vTg  = (ushort*)(ws + 22020096);       // [24][64][1024] bf16
  ushort* ff   = (ushort*)(ws + 25165824);       // [2048][4096] bf16
  ushort* wb   = (ushort*)(ws + 41943040);       // layer weights bf16
  ushort* hb   = (ushort*)(ws + 3145728);        // head chunk (overlay)
  float* projPart = (float*)(ws + 12582912);     // 2x6.29MB over qkv+vT
  float* ff2Part  = (float*)(ws + 9437184);      // 2x6.29MB over y+qkv

  const int oProj = 3 * Dm * Dm;
  const int oFF1  = oProj + Dm * Dm;
  const int oFF2  = oFF1 + DFF * Dm;

  embed_kernel<<<ROWS, 256, 0, stream>>>(idx, tok, pos, x);
  ln_kernel<<<ROWS, 256, 0, stream>>>(x, ln1w, ln1b, h);

  for (int l = 0; l < Ll; l++) {
    convert_w4<<<2048, 256, 0, stream>>>(
        qkvw + (size_t)l * 3 * Dm * Dm, projw + (size_t)l * Dm * Dm,
        ff1w + (size_t)l * DFF * Dm, ff2w + (size_t)l * Dm * DFF, wb,
        3 * Dm * Dm / 4, Dm * Dm / 4, DFF * Dm / 4, Dm * DFF / 4);
    gemm_mfma<EPI_QKV><<<dim3(18, 16), 256, 0, stream>>>(
        h, wb, qkvb + l * 3 * Dm, qkv, Dm, Dm, 3 * Dm, 3 * Dm);
    transpose_v<<<dim3(16, 24), 256, 0, stream>>>(qkv, vTg);
    attn_mfma<<<dim3(32, Hh, Bb), 128, 0, stream>>>(qkv, vTg, y);
    gemm_mfma<EPI_PART><<<dim3(6, 16, 2), 256, 0, stream>>>(
        y, wb + oProj, nullptr, projPart, Dm / 2, Dm, Dm, Dm);
    red_ln<<<ROWS, 256, 0, stream>>>(projPart, 2, projb + l * Dm, x,
                                     ln2w + l * Dm, ln2b + l * Dm, h);
    gemm_mfma<EPI_BIAS_GELU><<<dim3(32, 16), 256, 0, stream>>>(
        h, wb + oFF1, ff1b + l * DFF, ff, Dm, Dm, DFF, DFF);
    gemm_mfma<EPI_PART><<<dim3(6, 16, 2), 256, 0, stream>>>(
        ff, wb + oFF2, nullptr, ff2Part, DFF / 2, DFF, Dm, Dm);
    const float* nw = (l == Ll - 1) ? lnfw : ln1w + (l + 1) * Dm;
    const float* nb = (l == Ll - 1) ? lnfb : ln1b + (l + 1) * Dm;
    red_ln<<<ROWS, 256, 0, stream>>>(ff2Part, 2, ff2b + l * Dm, x, nw, nb, h);
  }

  const int ch0 = 25088;
  const int ch1 = Vv - ch0;
  convert_w<<<2048, 256, 0, stream>>>(headw, hb, ch0 * (Dm / 4));
  gemm_mfma<EPI_NONE><<<dim3(ch0 / 128, 16), 256, 0, stream>>>(
      h, hb, nullptr, out, Dm, Dm, ch0, Vv);
  convert_w<<<2048, 256, 0, stream>>>(headw + (size_t)ch0 * Dm, hb, ch1 * (Dm / 4));
  gemm_mfma<EPI_NONE><<<dim3((ch1 + 127) / 128, 16), 256, 0, stream>>>(
      h, hb, nullptr, out + ch0, Dm, Dm, ch1, Vv);
}